// Round 1
// baseline (1640.737 us; speedup 1.0000x reference)
//
#include <hip/hip_runtime.h>
#include <math.h>

#define KNN   10
#define NPTS  8192
#define NBAT  4
#define HID   64
#define NF    76

// ---------------------------------------------------------------------------
// Phase A: brute-force KNN, candidate dimension split 4-way per block.
// Block = 256 threads = 64 queries x 4 candidate-chunks. 512 blocks total
// (= 2048 waves -> 2 waves/SIMD across all 256 CUs).
// Tie semantics match jax.lax.top_k (stable, smaller index first): candidates
// processed in ascending global index order with strict '<' insertion, and
// the chunk merge consumes chunks in ascending order.
// ---------------------------------------------------------------------------
__global__ __launch_bounds__(256) void knn_kernel(const float* __restrict__ cloud,
                                                  int* __restrict__ knn_idx) {
    __shared__ float4 tile[256];              // 4 chunks x 64 candidates
    __shared__ float  pd[4][64][KNN];
    __shared__ int    pi[4][64][KNN];

    const int t  = threadIdx.x;
    const int c  = t >> 6;                    // chunk 0..3 (== wave id)
    const int ql = t & 63;                    // query slot in block
    const int bx = blockIdx.x;                // 0..511
    const int b  = bx >> 7;                   // batch
    const int n0 = (bx & 127) * 64;           // first query of block
    const int n  = n0 + ql;                   // batch-local query index

    const float* cb = cloud + (size_t)b * NPTS * 3;
    const float qx = cb[n * 3 + 0];
    const float qy = cb[n * 3 + 1];
    const float qz = cb[n * 3 + 2];
    const float qs = fmaf(qz, qz, fmaf(qy, qy, qx * qx));

    float bd[KNN];
    int   bi[KNN];
#pragma unroll
    for (int s = 0; s < KNN; ++s) { bd[s] = 3.4e38f; bi[s] = -1; }

    const int chunk_base = c * (NPTS / 4);    // 2048 candidates per chunk

    for (int i = 0; i < (NPTS / 4) / 64; ++i) {   // 32 tile iterations
        __syncthreads();
        const int cand = chunk_base + i * 64 + ql;    // this thread stages one cand
        const float x = cb[cand * 3 + 0];
        const float y = cb[cand * 3 + 1];
        const float z = cb[cand * 3 + 2];
        tile[t] = make_float4(x, y, z, fmaf(z, z, fmaf(y, y, x * x)));
        __syncthreads();

        const int jbase = chunk_base + i * 64;
        const int lbase = c * 64;
#pragma unroll 16
        for (int jj = 0; jj < 64; ++jj) {
            const float4 v = tile[lbase + jj];
            const int j = jbase + jj;
            const float dot = fmaf(v.z, qz, fmaf(v.y, qy, v.x * qx));
            const float d2 = fmaf(-2.0f, dot, qs + v.w);
            if (d2 < bd[KNN - 1] && j != n) {
                float d = d2; int id = j;
#pragma unroll
                for (int s = 0; s < KNN; ++s) {
                    if (d < bd[s]) {
                        float td = bd[s]; int ti = bi[s];
                        bd[s] = d; bi[s] = id;
                        d = td; id = ti;
                    }
                }
            }
        }
    }

    // publish partial lists
    __syncthreads();
#pragma unroll
    for (int s = 0; s < KNN; ++s) { pd[c][ql][s] = bd[s]; pi[c][ql][s] = bi[s]; }
    __syncthreads();

    // wave 0 merges: chunks in ascending order preserves stable tie-break
    if (t < 64) {
        float md[KNN]; int mi[KNN];
#pragma unroll
        for (int s = 0; s < KNN; ++s) { md[s] = 3.4e38f; mi[s] = -1; }
        for (int cc = 0; cc < 4; ++cc) {
#pragma unroll
            for (int s = 0; s < KNN; ++s) {
                float d = pd[cc][t][s]; int id = pi[cc][t][s];
                if (d < md[KNN - 1]) {
#pragma unroll
                    for (int u = 0; u < KNN; ++u) {
                        if (d < md[u]) {
                            float td = md[u]; int ti = mi[u];
                            md[u] = d; mi[u] = id;
                            d = td; id = ti;
                        }
                    }
                }
            }
        }
        int* outp = knn_idx + ((size_t)b * NPTS + (n0 + t)) * KNN;
#pragma unroll
        for (int s = 0; s < KNN; ++s) outp[s] = mi[s];
    }
}

// ---------------------------------------------------------------------------
// Phase B: features (center, neighbors, rel, dists, eigen-geometry) + MLP.
// Block = 64 threads (one point each), 512 blocks. W1/b1/W2/b2 staged in LDS,
// read as wave-uniform broadcasts.
// ---------------------------------------------------------------------------
__global__ __launch_bounds__(64) void feat_mlp_kernel(const float* __restrict__ cloud,
                                                      const float* __restrict__ W1,
                                                      const float* __restrict__ b1,
                                                      const float* __restrict__ W2,
                                                      const float* __restrict__ b2,
                                                      const int* __restrict__ knn_idx,
                                                      float* __restrict__ out) {
    __shared__ float w1s[NF * HID];
    __shared__ float b1s[HID];
    __shared__ float w2s[HID * 3];
    __shared__ float b2s[3];

    const int t = threadIdx.x;
    for (int idx = t; idx < NF * HID; idx += 64) w1s[idx] = W1[idx];
    if (t < HID) b1s[t] = b1[t];
    for (int idx = t; idx < HID * 3; idx += 64) w2s[idx] = W2[idx];
    if (t < 3) b2s[t] = b2[t];
    __syncthreads();

    const int gid = blockIdx.x * 64 + t;      // 0..32767
    const int b = gid >> 13;
    const int n = gid & (NPTS - 1);
    const float* cb = cloud + (size_t)b * NPTS * 3;

    const float cx = cb[n * 3 + 0];
    const float cy = cb[n * 3 + 1];
    const float cz = cb[n * 3 + 2];

    float nx[KNN], ny[KNN], nz[KNN];
    const int* ki = knn_idx + (size_t)gid * KNN;
#pragma unroll
    for (int k = 0; k < KNN; ++k) {
        const int j = ki[k];
        nx[k] = cb[j * 3 + 0];
        ny[k] = cb[j * 3 + 1];
        nz[k] = cb[j * 3 + 2];
    }

    float h[HID];
#pragma unroll
    for (int j = 0; j < HID; ++j) h[j] = b1s[j];

    auto acc = [&](int f, float v) {
        const float4* w4 = reinterpret_cast<const float4*>(w1s + f * HID);
#pragma unroll
        for (int j4 = 0; j4 < HID / 4; ++j4) {
            const float4 w = w4[j4];
            h[4 * j4 + 0] = fmaf(v, w.x, h[4 * j4 + 0]);
            h[4 * j4 + 1] = fmaf(v, w.y, h[4 * j4 + 1]);
            h[4 * j4 + 2] = fmaf(v, w.z, h[4 * j4 + 2]);
            h[4 * j4 + 3] = fmaf(v, w.w, h[4 * j4 + 3]);
        }
    };

    // f 0..2: center
    acc(0, cx); acc(1, cy); acc(2, cz);
    // f 3..32: neighbors (k-major, xyz)
#pragma unroll
    for (int k = 0; k < KNN; ++k) {
        acc(3 + 3 * k + 0, nx[k]);
        acc(3 + 3 * k + 1, ny[k]);
        acc(3 + 3 * k + 2, nz[k]);
    }
    // f 33..62: rel = neighbor - center
#pragma unroll
    for (int k = 0; k < KNN; ++k) {
        acc(33 + 3 * k + 0, nx[k] - cx);
        acc(33 + 3 * k + 1, ny[k] - cy);
        acc(33 + 3 * k + 2, nz[k] - cz);
    }
    // f 63..72: dists
#pragma unroll
    for (int k = 0; k < KNN; ++k) {
        const float rx = nx[k] - cx, ry = ny[k] - cy, rz = nz[k] - cz;
        acc(63 + k, sqrtf(fmaf(rz, rz, fmaf(ry, ry, rx * rx))));
    }

    // covariance of neighbors (unbiased, /(K-1))
    float mx = 0.f, my = 0.f, mz = 0.f;
#pragma unroll
    for (int k = 0; k < KNN; ++k) { mx += nx[k]; my += ny[k]; mz += nz[k]; }
    mx *= (1.0f / KNN); my *= (1.0f / KNN); mz *= (1.0f / KNN);
    float c00 = 0.f, c01 = 0.f, c02 = 0.f, c11 = 0.f, c12 = 0.f, c22 = 0.f;
#pragma unroll
    for (int k = 0; k < KNN; ++k) {
        const float ex = nx[k] - mx, ey = ny[k] - my, ez = nz[k] - mz;
        c00 = fmaf(ex, ex, c00); c01 = fmaf(ex, ey, c01); c02 = fmaf(ex, ez, c02);
        c11 = fmaf(ey, ey, c11); c12 = fmaf(ey, ez, c12); c22 = fmaf(ez, ez, c22);
    }
    const float sc = 1.0f / (KNN - 1);
    c00 *= sc; c01 *= sc; c02 *= sc; c11 *= sc; c12 *= sc; c22 *= sc;

    // closed-form symmetric 3x3 eigenvalues (fp64 for the trig path)
    const double a00 = c00, a01 = c01, a02 = c02, a11 = c11, a12 = c12, a22 = c22;
    const double q = (a00 + a11 + a22) / 3.0;
    const double p1 = a01 * a01 + a02 * a02 + a12 * a12;
    const double d00 = a00 - q, d11 = a11 - q, d22 = a22 - q;
    const double p2 = d00 * d00 + d11 * d11 + d22 * d22 + 2.0 * p1;
    double l1, l2, l3;
    if (p2 < 1e-300) {
        l1 = l2 = l3 = q;
    } else {
        const double p = sqrt(p2 / 6.0);
        const double inv = 1.0 / p;
        const double e00 = d00 * inv, e11 = d11 * inv, e22 = d22 * inv;
        const double e01 = a01 * inv, e02 = a02 * inv, e12 = a12 * inv;
        double detB = e00 * (e11 * e22 - e12 * e12)
                    - e01 * (e01 * e22 - e12 * e02)
                    + e02 * (e01 * e12 - e11 * e02);
        double r = 0.5 * detB;
        r = fmin(1.0, fmax(-1.0, r));
        const double phi = acos(r) / 3.0;
        l1 = q + 2.0 * p * cos(phi);                          // largest
        l3 = q + 2.0 * p * cos(phi + 2.0943951023931953);     // smallest
        l2 = 3.0 * q - l1 - l3;
    }
    const float lin = (float)((l1 - l2) / l1);
    const float pla = (float)((l2 - l3) / l1);
    const float sca = (float)(l3 / l1);
    acc(73, lin); acc(74, pla); acc(75, sca);

    // out = relu(relu(h) @ W2 + b2)
#pragma unroll
    for (int j = 0; j < HID; ++j) h[j] = fmaxf(h[j], 0.0f);
#pragma unroll
    for (int o = 0; o < 3; ++o) {
        float a = b2s[o];
#pragma unroll
        for (int j = 0; j < HID; ++j) a = fmaf(h[j], w2s[j * 3 + o], a);
        out[(size_t)gid * 3 + o] = fmaxf(a, 0.0f);
    }
}

extern "C" void kernel_launch(void* const* d_in, const int* in_sizes, int n_in,
                              void* d_out, int out_size, void* d_ws, size_t ws_size,
                              hipStream_t stream) {
    const float* cloud = (const float*)d_in[0];   // [4,8192,3]
    const float* W1    = (const float*)d_in[1];   // [76,64]
    const float* b1    = (const float*)d_in[2];   // [64]
    const float* W2    = (const float*)d_in[3];   // [64,3]
    const float* b2    = (const float*)d_in[4];   // [3]
    float* out = (float*)d_out;                   // [4,8192,3]

    int* knn = (int*)d_ws;                        // 4*8192*10 ints = 1.25 MB

    knn_kernel<<<dim3(512), dim3(256), 0, stream>>>(cloud, knn);
    feat_mlp_kernel<<<dim3(512), dim3(64), 0, stream>>>(cloud, W1, b1, W2, b2, knn, out);
}

// Round 2
// 342.082 us; speedup vs baseline: 4.7963x; 4.7963x over previous
//
#include <hip/hip_runtime.h>
#include <math.h>

#define KNN   10
#define NPTS  8192
#define HID   64
#define NF    76

// Large normal double used as "empty / excluded" sentinel key.
#define KEY_SENTINEL __longlong_as_double(0x7FE0000000000000LL)

// ---------------------------------------------------------------------------
// Phase A: brute-force KNN.
// Key trick: pack (monotone-mapped d2 bits, candidate index) into the
// mantissa of a normal positive double: bits = (1<<62) | (m<<13) | j.
// Ordering of these doubles == lexicographic (d2 asc, index asc) == jax
// stable top-k. A sorted-insert level is then just v_min_f64 + v_max_f64,
// run branchlessly for every candidate (divergent-guard buys nothing since
// with 64 lists/wave some lane inserts almost every step).
// Block = 512 threads = 64 queries x 8 candidate chunks -> 4096 waves
// (4 waves/SIMD). Merge is order-independent (keys are totally ordered).
// ---------------------------------------------------------------------------
__global__ __launch_bounds__(512) void knn_kernel(const float* __restrict__ cloud,
                                                  int* __restrict__ knn_idx) {
    __shared__ float4 tile[512];              // 8 chunks x 64 candidates
    __shared__ double pk[8][64][KNN + 1];     // +1 pad (bank spread)

    const int t  = threadIdx.x;
    const int c  = t >> 6;                    // chunk 0..7 (== wave id)
    const int ql = t & 63;                    // query slot
    const int bx = blockIdx.x;                // 0..511
    const int b  = bx >> 7;                   // batch
    const int n0 = (bx & 127) * 64;
    const int n  = n0 + ql;                   // batch-local query index

    const float* cb = cloud + (size_t)b * NPTS * 3;
    const float qx = cb[n * 3 + 0];
    const float qy = cb[n * 3 + 1];
    const float qz = cb[n * 3 + 2];
    const float qs = fmaf(qz, qz, fmaf(qy, qy, qx * qx));

    double bd[KNN];
#pragma unroll
    for (int s = 0; s < KNN; ++s) bd[s] = KEY_SENTINEL;

    const int chunk_base = c * (NPTS / 8);    // 1024 candidates per chunk

    for (int i = 0; i < (NPTS / 8) / 64; ++i) {   // 16 tile iterations
        __syncthreads();
        const int cand = chunk_base + i * 64 + ql;
        const float x = cb[cand * 3 + 0];
        const float y = cb[cand * 3 + 1];
        const float z = cb[cand * 3 + 2];
        tile[t] = make_float4(x, y, z, fmaf(z, z, fmaf(y, y, x * x)));
        __syncthreads();

        const int jbase = chunk_base + i * 64;
        const int lbase = c * 64;
#pragma unroll 16
        for (int jj = 0; jj < 64; ++jj) {
            const float4 v = tile[lbase + jj];       // wave-uniform broadcast
            const int j = jbase + jj;
            const float dot = fmaf(v.z, qz, fmaf(v.y, qy, v.x * qx));
            const float d2 = fmaf(-2.0f, dot, qs + v.w);
            // monotone map f32 -> u32 (handles possible tiny-negative d2)
            const unsigned int fb = __float_as_uint(d2);
            const unsigned int m =
                fb ^ ((unsigned int)((int)fb >> 31) | 0x80000000u);
            const unsigned long long kb =
                (1ULL << 62) | ((unsigned long long)m << 13) | (unsigned long long)j;
            double key = __longlong_as_double((long long)kb);
            key = (j == n) ? KEY_SENTINEL : key;     // self-exclusion
            // branchless sorted insert: 10 x (min_f64 + max_f64)
#pragma unroll
            for (int s = 0; s < KNN; ++s) {
                const double lo = fmin(bd[s], key);
                key = fmax(bd[s], key);
                bd[s] = lo;
            }
        }
    }

    __syncthreads();
#pragma unroll
    for (int s = 0; s < KNN; ++s) pk[c][ql][s] = bd[s];
    __syncthreads();

    // wave 0 merges the 8 partial lists (keys totally ordered -> any order ok)
    if (t < 64) {
        double md[KNN];
#pragma unroll
        for (int s = 0; s < KNN; ++s) md[s] = KEY_SENTINEL;
        for (int cc = 0; cc < 8; ++cc) {
#pragma unroll
            for (int s = 0; s < KNN; ++s) {
                double key = pk[cc][t][s];
#pragma unroll
                for (int u = 0; u < KNN; ++u) {
                    const double lo = fmin(md[u], key);
                    key = fmax(md[u], key);
                    md[u] = lo;
                }
            }
        }
        int* outp = knn_idx + ((size_t)b * NPTS + (n0 + t)) * KNN;
#pragma unroll
        for (int s = 0; s < KNN; ++s)
            outp[s] = (int)((unsigned int)__double_as_longlong(md[s]) & 8191u);
    }
}

// ---------------------------------------------------------------------------
// Phase B: features + MLP. Fix vs R0: no lambda / no address-taken register
// array. Per-thread features go to LDS (fs[64][77], odd stride => the 2-way
// lane aliasing is free); h[64] stays in registers with constant indexing
// (inner j-loops fully unrolled). Weights staged in LDS, wave-uniform reads.
// ---------------------------------------------------------------------------
__global__ __launch_bounds__(64) void feat_mlp_kernel(const float* __restrict__ cloud,
                                                      const float* __restrict__ W1,
                                                      const float* __restrict__ b1,
                                                      const float* __restrict__ W2,
                                                      const float* __restrict__ b2,
                                                      const int* __restrict__ knn_idx,
                                                      float* __restrict__ out) {
    __shared__ float w1s[NF * HID];
    __shared__ float b1s[HID];
    __shared__ float w2s[HID * 3];
    __shared__ float b2s[3];
    __shared__ float fs[64][NF + 1];          // +1 pad: stride 77 (odd)

    const int t = threadIdx.x;
    for (int idx = t; idx < NF * HID; idx += 64) w1s[idx] = W1[idx];
    b1s[t] = b1[t];
    for (int idx = t; idx < HID * 3; idx += 64) w2s[idx] = W2[idx];
    if (t < 3) b2s[t] = b2[t];

    const int gid = blockIdx.x * 64 + t;      // 0..32767
    const int b = gid >> 13;
    const int n = gid & (NPTS - 1);
    const float* cb = cloud + (size_t)b * NPTS * 3;

    const float cx = cb[n * 3 + 0];
    const float cy = cb[n * 3 + 1];
    const float cz = cb[n * 3 + 2];

    float nx[KNN], ny[KNN], nz[KNN];
    const int* ki = knn_idx + (size_t)gid * KNN;
#pragma unroll
    for (int k = 0; k < KNN; ++k) {
        const int j = ki[k];
        nx[k] = cb[j * 3 + 0];
        ny[k] = cb[j * 3 + 1];
        nz[k] = cb[j * 3 + 2];
    }

    float* fr = fs[t];
    fr[0] = cx; fr[1] = cy; fr[2] = cz;
#pragma unroll
    for (int k = 0; k < KNN; ++k) {
        fr[3 + 3 * k + 0] = nx[k];
        fr[3 + 3 * k + 1] = ny[k];
        fr[3 + 3 * k + 2] = nz[k];
    }
#pragma unroll
    for (int k = 0; k < KNN; ++k) {
        fr[33 + 3 * k + 0] = nx[k] - cx;
        fr[33 + 3 * k + 1] = ny[k] - cy;
        fr[33 + 3 * k + 2] = nz[k] - cz;
    }
#pragma unroll
    for (int k = 0; k < KNN; ++k) {
        const float rx = nx[k] - cx, ry = ny[k] - cy, rz = nz[k] - cz;
        fr[63 + k] = sqrtf(fmaf(rz, rz, fmaf(ry, ry, rx * rx)));
    }

    // covariance of neighbors (unbiased, /(K-1))
    float mx = 0.f, my = 0.f, mz = 0.f;
#pragma unroll
    for (int k = 0; k < KNN; ++k) { mx += nx[k]; my += ny[k]; mz += nz[k]; }
    mx *= (1.0f / KNN); my *= (1.0f / KNN); mz *= (1.0f / KNN);
    float c00 = 0.f, c01 = 0.f, c02 = 0.f, c11 = 0.f, c12 = 0.f, c22 = 0.f;
#pragma unroll
    for (int k = 0; k < KNN; ++k) {
        const float ex = nx[k] - mx, ey = ny[k] - my, ez = nz[k] - mz;
        c00 = fmaf(ex, ex, c00); c01 = fmaf(ex, ey, c01); c02 = fmaf(ex, ez, c02);
        c11 = fmaf(ey, ey, c11); c12 = fmaf(ey, ez, c12); c22 = fmaf(ez, ez, c22);
    }
    const float sc = 1.0f / (KNN - 1);
    c00 *= sc; c01 *= sc; c02 *= sc; c11 *= sc; c12 *= sc; c22 *= sc;

    // closed-form symmetric 3x3 eigenvalues (fp64 trig path)
    const double a00 = c00, a01 = c01, a02 = c02, a11 = c11, a12 = c12, a22 = c22;
    const double q = (a00 + a11 + a22) / 3.0;
    const double p1 = a01 * a01 + a02 * a02 + a12 * a12;
    const double d00 = a00 - q, d11 = a11 - q, d22 = a22 - q;
    const double p2 = d00 * d00 + d11 * d11 + d22 * d22 + 2.0 * p1;
    double l1, l2, l3;
    if (p2 < 1e-300) {
        l1 = l2 = l3 = q;
    } else {
        const double p = sqrt(p2 / 6.0);
        const double inv = 1.0 / p;
        const double e00 = d00 * inv, e11 = d11 * inv, e22 = d22 * inv;
        const double e01 = a01 * inv, e02 = a02 * inv, e12 = a12 * inv;
        double detB = e00 * (e11 * e22 - e12 * e12)
                    - e01 * (e01 * e22 - e12 * e02)
                    + e02 * (e01 * e12 - e11 * e02);
        double r = 0.5 * detB;
        r = fmin(1.0, fmax(-1.0, r));
        const double phi = acos(r) / 3.0;
        l1 = q + 2.0 * p * cos(phi);                          // largest
        l3 = q + 2.0 * p * cos(phi + 2.0943951023931953);     // smallest
        l2 = 3.0 * q - l1 - l3;
    }
    fr[73] = (float)((l1 - l2) / l1);
    fr[74] = (float)((l2 - l3) / l1);
    fr[75] = (float)(l3 / l1);

    __syncthreads();   // weights + own features visible

    float h[HID];
#pragma unroll
    for (int j = 0; j < HID; ++j) h[j] = b1s[j];

#pragma unroll 4
    for (int f = 0; f < NF; ++f) {
        const float v = fr[f];
        const float4* w4 = reinterpret_cast<const float4*>(w1s + f * HID);
#pragma unroll
        for (int j4 = 0; j4 < HID / 4; ++j4) {
            const float4 w = w4[j4];
            h[4 * j4 + 0] = fmaf(v, w.x, h[4 * j4 + 0]);
            h[4 * j4 + 1] = fmaf(v, w.y, h[4 * j4 + 1]);
            h[4 * j4 + 2] = fmaf(v, w.z, h[4 * j4 + 2]);
            h[4 * j4 + 3] = fmaf(v, w.w, h[4 * j4 + 3]);
        }
    }

    float o0 = b2s[0], o1 = b2s[1], o2 = b2s[2];
#pragma unroll
    for (int j = 0; j < HID; ++j) {
        const float r = fmaxf(h[j], 0.0f);
        o0 = fmaf(r, w2s[j * 3 + 0], o0);
        o1 = fmaf(r, w2s[j * 3 + 1], o1);
        o2 = fmaf(r, w2s[j * 3 + 2], o2);
    }
    float* op = out + (size_t)gid * 3;
    op[0] = fmaxf(o0, 0.0f);
    op[1] = fmaxf(o1, 0.0f);
    op[2] = fmaxf(o2, 0.0f);
}

extern "C" void kernel_launch(void* const* d_in, const int* in_sizes, int n_in,
                              void* d_out, int out_size, void* d_ws, size_t ws_size,
                              hipStream_t stream) {
    const float* cloud = (const float*)d_in[0];   // [4,8192,3]
    const float* W1    = (const float*)d_in[1];   // [76,64]
    const float* b1    = (const float*)d_in[2];   // [64]
    const float* W2    = (const float*)d_in[3];   // [64,3]
    const float* b2    = (const float*)d_in[4];   // [3]
    float* out = (float*)d_out;                   // [4,8192,3]

    int* knn = (int*)d_ws;                        // 4*8192*10 ints = 1.25 MB

    knn_kernel<<<dim3(512), dim3(512), 0, stream>>>(cloud, knn);
    feat_mlp_kernel<<<dim3(512), dim3(64), 0, stream>>>(cloud, W1, b1, W2, b2, knn, out);
}